// Round 10
// baseline (113.922 us; speedup 1.0000x reference)
//
#include <hip/hip_runtime.h>

#define IN_DIM 128
#define OUT_DIM 64
#define RPB_SHIFT 6
#define RPB 64           // rows per bucket (pow2)
#define SUBCAP 176       // capacity per (bucket, block-group) sub-slab (mean 80, +10 sigma)
#define SLABCAP 896      // LDS sorted capacity per bucket (mean 640, +10 sigma)

typedef __attribute__((ext_vector_type(8))) short bf16x8;
typedef __attribute__((ext_vector_type(4))) float f32x4;
typedef __attribute__((ext_vector_type(4))) unsigned short us4;

__device__ inline unsigned short f2bf(float f) {  // RNE f32 -> bf16 bits
  unsigned u = __float_as_uint(f);
  u += 0x7FFFu + ((u >> 16) & 1u);
  return (unsigned short)(u >> 16);
}

// ---------------- prep: zero cursors (blocks 0-7) + build WT bf16 (blocks 8-15) --------
__global__ __launch_bounds__(256) void prep_kernel(const float* __restrict__ W,
                                                   unsigned short* __restrict__ WT,
                                                   int* __restrict__ cursor, int ncur) {
  const int bid = blockIdx.x, t = threadIdx.x;
  if (bid < 8) {
    for (int i = bid * 256 + t; i < ncur; i += 8 * 256) cursor[i] = 0;
  } else {
    int gid = (bid - 8) * 256 + t;   // 0..2047, one us4 each
    int c = gid >> 5;                // col 0..63
    int kb = (gid & 31) * 4;         // k base
    us4 p;
    p.x = f2bf(W[(kb + 0) * OUT_DIM + c]);
    p.y = f2bf(W[(kb + 1) * OUT_DIM + c]);
    p.z = f2bf(W[(kb + 2) * OUT_DIM + c]);
    p.w = f2bf(W[(kb + 3) * OUT_DIM + c]);
    *(us4*)(WT + c * IN_DIM + kb) = p;
  }
}

// ---------------- gemm: no-LDS MFMA. A direct from global X, B from WT (L2-hot) -------
// 256 thr = 4 waves x 16 rows; each wave: 16 rows x 64 cols, 16 MFMAs.
// A-frag: lane holds X row (lane&15), k=(lane>>4)*8..+7 ; wave's loads = 16 x 64B lines.
__global__ __launch_bounds__(256) void gemm_kernel(const float* __restrict__ X,
                                                   const unsigned short* __restrict__ WT,
                                                   unsigned short* __restrict__ H, int n) {
  const int t = threadIdx.x;
  const int lane = t & 63;
  const int sub = t >> 6;           // 0..3: row quad
  const int row0 = blockIdx.x * 64;
  const int r16 = lane & 15;
  const int kg = (lane >> 4) * 8;
  const int rowA = min(row0 + sub * 16 + r16, n - 1);  // clamp: OOB rows never stored
  const float* xr = X + (size_t)rowA * IN_DIM + kg;

  f32x4 acc[4] = {};
#pragma unroll
  for (int kk = 0; kk < 4; ++kk) {
    float4 u = *(const float4*)(xr + kk * 32);
    float4 v = *(const float4*)(xr + kk * 32 + 4);
    bf16x8 a;
    a[0] = (short)f2bf(u.x); a[1] = (short)f2bf(u.y);
    a[2] = (short)f2bf(u.z); a[3] = (short)f2bf(u.w);
    a[4] = (short)f2bf(v.x); a[5] = (short)f2bf(v.y);
    a[6] = (short)f2bf(v.z); a[7] = (short)f2bf(v.w);
#pragma unroll
    for (int ct = 0; ct < 4; ++ct) {
      bf16x8 b = *(const bf16x8*)(WT + (ct * 16 + r16) * IN_DIM + kk * 32 + kg);
      acc[ct] = __builtin_amdgcn_mfma_f32_16x16x32_bf16(a, b, acc[ct], 0, 0, 0);
    }
  }

  const int orow0 = row0 + sub * 16 + (lane >> 4) * 4;
#pragma unroll
  for (int ct = 0; ct < 4; ++ct) {
    int col = ct * 16 + r16;
#pragma unroll
    for (int r = 0; r < 4; ++r) {
      int row = orow0 + r;
      if (row < n) H[(size_t)row * OUT_DIM + col] = f2bf(acc[ct][r]);
    }
  }
}

// ---------------- scatter: per-edge atomic into XCD-local sub-slab ----------------
// Sub-slab g = blockIdx&7: consecutive blocks round-robin XCDs, so each sub-slab's
// lines are written by (mostly) one XCD -> no cross-XCD line bounce / write amp.
__global__ __launch_bounds__(256) void scatter_kernel(const int* __restrict__ rows,
                                                      const int* __restrict__ cols,
                                                      const float* __restrict__ vals,
                                                      int* __restrict__ cursor,
                                                      uint2* __restrict__ staged, int ne) {
  const int g = blockIdx.x & 7;
  for (int i = blockIdx.x * 256 + threadIdx.x; i < ne; i += gridDim.x * 256) {
    int r = rows[i];
    int slot = ((r >> RPB_SHIFT) << 3) + g;
    int pos = atomicAdd(&cursor[slot], 1);
    if (pos < SUBCAP) {
      unsigned key = ((unsigned)(r & (RPB - 1)) << 17) | (unsigned)cols[i];
      staged[(size_t)slot * SUBCAP + pos] = make_uint2(key, __float_as_uint(vals[i]));
    }
  }
}

// ---------------- fused: 8-seg ingest + LDS row-sort + gather + bias + ReLU ----------
__global__ __launch_bounds__(512) void spmm_fused_kernel(const int* __restrict__ cursor,
                                                         const uint2* __restrict__ staged,
                                                         const unsigned short* __restrict__ H,
                                                         const float* __restrict__ bias,
                                                         float* __restrict__ out, int n) {
  __shared__ uint2 sorted[SLABCAP];
  __shared__ int rcnt[RPB];
  __shared__ int rstart[RPB];
  __shared__ int rcur[RPB];
  __shared__ int segc[8];

  const int b = blockIdx.x;
  const int t = threadIdx.x;
  const int lane = t & 63;
  const int wave = t >> 6;  // 0..7

  if (t < 8) segc[t] = min(cursor[b * 8 + t], SUBCAP);
  if (t < RPB) rcnt[t] = 0;
  __syncthreads();
  if (t == 0) {  // clamp so total <= SLABCAP (never triggers in practice)
    int s = 0;
    for (int j = 0; j < 8; ++j) {
      int c = segc[j];
      if (s + c > SLABCAP) c = SLABCAP - s;
      segc[j] = c;
      s += c;
    }
  }
  __syncthreads();

  // hist: wave j handles segment j
  {
    const uint2* seg = staged + (size_t)(b * 8 + wave) * SUBCAP;
    const int c = segc[wave];
    for (int i = lane; i < c; i += 64) atomicAdd(&rcnt[seg[i].x >> 17], 1);
  }
  __syncthreads();

  // wave-level exclusive scan of rcnt[0..63]
  if (t < RPB) {
    int v = rcnt[t];
    int x = v;
#pragma unroll
    for (int d = 1; d < RPB; d <<= 1) {
      int y = __shfl_up(x, d);
      if (t >= d) x += y;
    }
    rstart[t] = x - v;
    rcur[t] = x - v;
  }
  __syncthreads();

  // scatter into row-sorted LDS order: wave j handles segment j
  {
    const uint2* seg = staged + (size_t)(b * 8 + wave) * SUBCAP;
    const int c = segc[wave];
    for (int i = lane; i < c; i += 64) {
      uint2 e = seg[i];
      int pos = atomicAdd(&rcur[e.x >> 17], 1);
      sorted[pos] = e;
    }
  }
  __syncthreads();

  // gather: 16-lane groups, lane = 4 dims (uint2 of bf16); group owns its own rows.
  const int q4 = (lane & 15) * 4;
  const float4 bv = *(const float4*)&bias[q4];
  const int row0 = b << RPB_SHIFT;

  for (int rl = wave * 4 + ((lane >> 4) & 3); rl < RPB; rl += 32) {
    const int s = rstart[rl];
    const int c = rcnt[rl];
    float a0 = 0.f, a1 = 0.f, a2 = 0.f, a3 = 0.f;
    int e = 0;
    for (; e + 4 <= c; e += 4) {
      float v[4];
      uint2 hu[4];
#pragma unroll
      for (int k = 0; k < 4; ++k) {
        uint2 en = sorted[s + e + k];
        hu[k] = *(const uint2*)&H[(size_t)(en.x & 0x1FFFF) * OUT_DIM + q4];
        v[k] = __uint_as_float(en.y);
      }
#pragma unroll
      for (int k = 0; k < 4; ++k) {
        a0 = fmaf(v[k], __uint_as_float(hu[k].x << 16), a0);
        a1 = fmaf(v[k], __uint_as_float(hu[k].x & 0xFFFF0000u), a1);
        a2 = fmaf(v[k], __uint_as_float(hu[k].y << 16), a2);
        a3 = fmaf(v[k], __uint_as_float(hu[k].y & 0xFFFF0000u), a3);
      }
    }
    for (; e < c; ++e) {
      uint2 en = sorted[s + e];
      uint2 hu = *(const uint2*)&H[(size_t)(en.x & 0x1FFFF) * OUT_DIM + q4];
      float v = __uint_as_float(en.y);
      a0 = fmaf(v, __uint_as_float(hu.x << 16), a0);
      a1 = fmaf(v, __uint_as_float(hu.x & 0xFFFF0000u), a1);
      a2 = fmaf(v, __uint_as_float(hu.y << 16), a2);
      a3 = fmaf(v, __uint_as_float(hu.y & 0xFFFF0000u), a3);
    }
    int row = row0 + rl;
    if (row < n) {
      float4 o;
      o.x = fmaxf(a0 + bv.x, 0.f);
      o.y = fmaxf(a1 + bv.y, 0.f);
      o.z = fmaxf(a2 + bv.z, 0.f);
      o.w = fmaxf(a3 + bv.w, 0.f);
      *(float4*)(out + (size_t)row * OUT_DIM + q4) = o;
    }
  }
}

extern "C" void kernel_launch(void* const* d_in, const int* in_sizes, int n_in,
                              void* d_out, int out_size, void* d_ws, size_t ws_size,
                              hipStream_t stream) {
  const float* X    = (const float*)d_in[0];
  const int*   rows = (const int*)d_in[1];
  const int*   cols = (const int*)d_in[2];
  const float* vals = (const float*)d_in[3];
  const float* W    = (const float*)d_in[4];
  const float* bias = (const float*)d_in[5];
  float* out = (float*)d_out;

  const int n_nodes = in_sizes[0] / IN_DIM;
  const int n_edges = in_sizes[1];
  const int nb = (n_nodes + RPB - 1) >> RPB_SHIFT;      // 1563

  // workspace layout
  char* ws = (char*)d_ws;
  unsigned short* H = (unsigned short*)ws;               // n_nodes*64*2 = 12.8 MB
  size_t off = (size_t)n_nodes * OUT_DIM * sizeof(unsigned short);
  off = (off + 255) & ~(size_t)255;
  unsigned short* WT = (unsigned short*)(ws + off); off += OUT_DIM * IN_DIM * 2;  // 16 KB
  off = (off + 255) & ~(size_t)255;
  int* cursor = (int*)(ws + off); off += (size_t)nb * 8 * 4;                      // 50 KB
  off = (off + 255) & ~(size_t)255;
  uint2* staged = (uint2*)(ws + off);                    // nb*8*SUBCAP*8 = 17.6 MB

  prep_kernel<<<16, 256, 0, stream>>>(W, WT, cursor, nb * 8);
  gemm_kernel<<<nb, 256, 0, stream>>>(X, WT, H, n_nodes);
  scatter_kernel<<<2048, 256, 0, stream>>>(rows, cols, vals, cursor, staged, n_edges);
  spmm_fused_kernel<<<nb, 512, 0, stream>>>(cursor, staged, H, bias, out, n_nodes);
}

// Round 11
// 70.155 us; speedup vs baseline: 1.6239x; 1.6239x over previous
//
#include <hip/hip_runtime.h>

#define IN_DIM 128
#define OUT_DIM 64
#define RPB_SHIFT 6
#define RPB 64           // rows per bucket (pow2)
#define NBMAX 2048       // max buckets (n_nodes/RPB = 1563)
#define CHUNK 4096       // edges per partition block
#define SLABCAP 896      // slab capacity per bucket (mean 640, +10 sigma)
#define GROWS 128        // rows per gemm block (8 waves x 16 rows)

typedef __attribute__((ext_vector_type(8))) short bf16x8;
typedef __attribute__((ext_vector_type(4))) float f32x4;
typedef __attribute__((ext_vector_type(4))) unsigned short us4;

__device__ inline unsigned short f2bf(float f) {  // RNE f32 -> bf16 bits
  unsigned u = __float_as_uint(f);
  u += 0x7FFFu + ((u >> 16) & 1u);
  return (unsigned short)(u >> 16);
}

// ---------------- prep: zero cursors (blocks 0-7) + build WT bf16 (blocks 8-15) --------
__global__ __launch_bounds__(256) void prep_kernel(const float* __restrict__ W,
                                                   unsigned short* __restrict__ WT,
                                                   int* __restrict__ cursor, int ncur) {
  const int bid = blockIdx.x, t = threadIdx.x;
  if (bid < 8) {
    for (int i = bid * 256 + t; i < ncur; i += 8 * 256) cursor[i] = 0;
  } else {
    int gid = (bid - 8) * 256 + t;   // 0..2047, one us4 each
    int c = gid >> 5;                // col 0..63
    int kb = (gid & 31) * 4;         // k base
    us4 p;
    p.x = f2bf(W[(kb + 0) * OUT_DIM + c]);
    p.y = f2bf(W[(kb + 1) * OUT_DIM + c]);
    p.z = f2bf(W[(kb + 2) * OUT_DIM + c]);
    p.w = f2bf(W[(kb + 3) * OUT_DIM + c]);
    *(us4*)(WT + c * IN_DIM + kb) = p;
  }
}

// ---------------- fat kernel: partition (blocks < nPart) ∥ no-LDS gemm (rest) ---------
// Partition body: LDS hist + one global atomic per (block,bucket) reservation.
// Gemm body: zero LDS — A-frags direct from global X (fp32->bf16 in regs), B from WT.
__global__ __launch_bounds__(512) void fat_kernel(const float* __restrict__ X,
                                                  const unsigned short* __restrict__ WT,
                                                  unsigned short* __restrict__ H,
                                                  const int* __restrict__ rows,
                                                  const int* __restrict__ cols,
                                                  const float* __restrict__ vals,
                                                  int* __restrict__ cursor,
                                                  uint2* __restrict__ staged,
                                                  int n, int ne, int nb, int nPart) {
  __shared__ int lh[NBMAX];
  __shared__ int lbase[NBMAX];
  const int t = threadIdx.x;

  if ((int)blockIdx.x < nPart) {
    // ---------------- partition body ----------------
    const int e0 = blockIdx.x * CHUNK;
    const int e1 = min(e0 + CHUNK, ne);

    for (int i = t; i < nb; i += 512) lh[i] = 0;
    __syncthreads();

    for (int i = e0 + t; i < e1; i += 512)
      atomicAdd(&lh[rows[i] >> RPB_SHIFT], 1);
    __syncthreads();

    for (int i = t; i < nb; i += 512) {
      int c = lh[i];
      lbase[i] = c ? atomicAdd(&cursor[i], c) : 0;  // slab-relative offset
    }
    __syncthreads();
    for (int i = t; i < nb; i += 512) lh[i] = 0;
    __syncthreads();

    for (int i = e0 + t; i < e1; i += 512) {
      int r = rows[i];  // re-read; L2-hot
      int b = r >> RPB_SHIFT;
      int lofs = atomicAdd(&lh[b], 1);
      int pos = lbase[b] + lofs;
      if (pos < SLABCAP) {
        unsigned key = ((unsigned)(r & (RPB - 1)) << 17) | (unsigned)cols[i];
        staged[(size_t)b * SLABCAP + pos] = make_uint2(key, __float_as_uint(vals[i]));
      }
    }
  } else {
    // ---------------- gemm body: 128 rows, 8 waves x 16 rows, zero LDS ----------------
    const int lane = t & 63;
    const int wave = t >> 6;          // 0..7: row quad
    const int row0 = ((int)blockIdx.x - nPart) * GROWS;
    const int r16 = lane & 15;
    const int kg = (lane >> 4) * 8;
    const int rowA = min(row0 + wave * 16 + r16, n - 1);  // clamp: OOB rows never stored
    const float* xr = X + (size_t)rowA * IN_DIM + kg;

    f32x4 acc[4] = {};
#pragma unroll
    for (int kk = 0; kk < 4; ++kk) {
      float4 u = *(const float4*)(xr + kk * 32);
      float4 v = *(const float4*)(xr + kk * 32 + 4);
      bf16x8 a;
      a[0] = (short)f2bf(u.x); a[1] = (short)f2bf(u.y);
      a[2] = (short)f2bf(u.z); a[3] = (short)f2bf(u.w);
      a[4] = (short)f2bf(v.x); a[5] = (short)f2bf(v.y);
      a[6] = (short)f2bf(v.z); a[7] = (short)f2bf(v.w);
#pragma unroll
      for (int ct = 0; ct < 4; ++ct) {
        bf16x8 b = *(const bf16x8*)(WT + (ct * 16 + r16) * IN_DIM + kk * 32 + kg);
        acc[ct] = __builtin_amdgcn_mfma_f32_16x16x32_bf16(a, b, acc[ct], 0, 0, 0);
      }
    }

    const int orow0 = row0 + wave * 16 + (lane >> 4) * 4;
#pragma unroll
    for (int ct = 0; ct < 4; ++ct) {
      int col = ct * 16 + r16;
#pragma unroll
      for (int r = 0; r < 4; ++r) {
        int row = orow0 + r;
        if (row < n) H[(size_t)row * OUT_DIM + col] = f2bf(acc[ct][r]);
      }
    }
  }
}

// ---------------- fused: LDS row-sort + SpMM(bf16 H) + bias + ReLU ----------------
// One block per 64-row slab. Gather: 16-lane groups, lane = 4 dims (uint2 of bf16);
// each group owns its own rows -> no cross-group reduction, float4 stores.
__global__ __launch_bounds__(512) void spmm_fused_kernel(const int* __restrict__ cursor,
                                                         const uint2* __restrict__ staged,
                                                         const unsigned short* __restrict__ H,
                                                         const float* __restrict__ bias,
                                                         float* __restrict__ out, int n) {
  __shared__ uint2 sorted[SLABCAP];
  __shared__ int rcnt[RPB];
  __shared__ int rstart[RPB];
  __shared__ int rcur[RPB];

  const int b = blockIdx.x;
  const int t = threadIdx.x;
  const int cnt = min(cursor[b], SLABCAP);
  const uint2* slab = staged + (size_t)b * SLABCAP;

  if (t < RPB) rcnt[t] = 0;
  __syncthreads();
  for (int i = t; i < cnt; i += 512) atomicAdd(&rcnt[slab[i].x >> 17], 1);
  __syncthreads();

  // wave-level exclusive scan of rcnt[0..63] (wave 0, no barriers inside)
  if (t < RPB) {
    int v = rcnt[t];
    int x = v;
#pragma unroll
    for (int d = 1; d < RPB; d <<= 1) {
      int y = __shfl_up(x, d);
      if (t >= d) x += y;
    }
    rstart[t] = x - v;
    rcur[t] = x - v;
  }
  __syncthreads();

  // scatter into row-sorted LDS order
  for (int i = t; i < cnt; i += 512) {
    uint2 e = slab[i];
    int rl = e.x >> 17;
    int pos = atomicAdd(&rcur[rl], 1);
    sorted[pos] = e;
  }
  __syncthreads();

  // gather phase
  const int lane = t & 63;
  const int wave = t >> 6;          // 0..7
  const int q4 = (lane & 15) * 4;   // dims q4..q4+3
  const float4 bv = *(const float4*)&bias[q4];
  const int row0 = b << RPB_SHIFT;

  for (int rl = wave * 4 + ((lane >> 4) & 3); rl < RPB; rl += 32) {
    const int s = rstart[rl];
    const int c = rcnt[rl];
    float a0 = 0.f, a1 = 0.f, a2 = 0.f, a3 = 0.f;
    int e = 0;
    for (; e + 4 <= c; e += 4) {
      float v[4];
      uint2 hu[4];
#pragma unroll
      for (int k = 0; k < 4; ++k) {
        uint2 en = sorted[s + e + k];
        hu[k] = *(const uint2*)&H[(size_t)(en.x & 0x1FFFF) * OUT_DIM + q4];
        v[k] = __uint_as_float(en.y);
      }
#pragma unroll
      for (int k = 0; k < 4; ++k) {
        a0 = fmaf(v[k], __uint_as_float(hu[k].x << 16), a0);
        a1 = fmaf(v[k], __uint_as_float(hu[k].x & 0xFFFF0000u), a1);
        a2 = fmaf(v[k], __uint_as_float(hu[k].y << 16), a2);
        a3 = fmaf(v[k], __uint_as_float(hu[k].y & 0xFFFF0000u), a3);
      }
    }
    for (; e < c; ++e) {
      uint2 en = sorted[s + e];
      uint2 hu = *(const uint2*)&H[(size_t)(en.x & 0x1FFFF) * OUT_DIM + q4];
      float v = __uint_as_float(en.y);
      a0 = fmaf(v, __uint_as_float(hu.x << 16), a0);
      a1 = fmaf(v, __uint_as_float(hu.x & 0xFFFF0000u), a1);
      a2 = fmaf(v, __uint_as_float(hu.y << 16), a2);
      a3 = fmaf(v, __uint_as_float(hu.y & 0xFFFF0000u), a3);
    }
    int row = row0 + rl;
    if (row < n) {
      float4 o;
      o.x = fmaxf(a0 + bv.x, 0.f);
      o.y = fmaxf(a1 + bv.y, 0.f);
      o.z = fmaxf(a2 + bv.z, 0.f);
      o.w = fmaxf(a3 + bv.w, 0.f);
      *(float4*)(out + (size_t)row * OUT_DIM + q4) = o;
    }
  }
}

extern "C" void kernel_launch(void* const* d_in, const int* in_sizes, int n_in,
                              void* d_out, int out_size, void* d_ws, size_t ws_size,
                              hipStream_t stream) {
  const float* X    = (const float*)d_in[0];
  const int*   rows = (const int*)d_in[1];
  const int*   cols = (const int*)d_in[2];
  const float* vals = (const float*)d_in[3];
  const float* W    = (const float*)d_in[4];
  const float* bias = (const float*)d_in[5];
  float* out = (float*)d_out;

  const int n_nodes = in_sizes[0] / IN_DIM;
  const int n_edges = in_sizes[1];
  const int nb = (n_nodes + RPB - 1) >> RPB_SHIFT;      // 1563

  // workspace layout
  char* ws = (char*)d_ws;
  unsigned short* H = (unsigned short*)ws;               // n_nodes*64*2 = 12.8 MB
  size_t off = (size_t)n_nodes * OUT_DIM * sizeof(unsigned short);
  off = (off + 255) & ~(size_t)255;
  unsigned short* WT = (unsigned short*)(ws + off); off += OUT_DIM * IN_DIM * 2;  // 16 KB
  off = (off + 255) & ~(size_t)255;
  int* cursor = (int*)(ws + off); off += (size_t)NBMAX * 4;
  off = (off + 255) & ~(size_t)255;
  uint2* staged = (uint2*)(ws + off);                    // nb * SLABCAP * 8 = 11.2 MB

  const int nPart = (n_edges + CHUNK - 1) / CHUNK;       // 245
  const int nGemm = (n_nodes + GROWS - 1) / GROWS;       // 782

  prep_kernel<<<16, 256, 0, stream>>>(W, WT, cursor, nb);
  fat_kernel<<<nPart + nGemm, 512, 0, stream>>>(X, WT, H, rows, cols, vals, cursor, staged,
                                                n_nodes, n_edges, nb, nPart);
  spmm_fused_kernel<<<nb, 512, 0, stream>>>(cursor, staged, H, bias, out, n_nodes);
}